// Round 6
// baseline (781.214 us; speedup 1.0000x reference)
//
#include <hip/hip_runtime.h>
#include <hip/hip_bf16.h>

#define NB    15
#define NMC   10000
#define NTR   20000
#define NTE   10000
#define BSZ   1024
#define NCLS  10

// KDE constants: BW=0.3, KDE_NORM = 2*pi*BW*BW
// k = exp(-d2/(2*BW*BW)) = exp2(-d2 * C), C = log2(e)/(2*BW*BW)
#define KDE_NORM  0.5654866776461628f
#define EXPC      8.014972449383130f    /* log2(e)/0.18 */
#define TWO_EXPC  16.029944898766260f   /* 2*EXPC */

#define DS    17     // data slices (blockIdx.z): 5*15*17=1275 blocks ~ 4.98/CU
#define TILE  256    // data points staged per round
#define MQ    8      // MC points per thread (4 v2f pairs)

typedef float v2f __attribute__((ext_vector_type(2)));
typedef float v4f __attribute__((ext_vector_type(4)));

// ws float layout:
//  [0]        cnt
//  [1..15]    hist_tr
//  [16..30]   hist_te
//  [32..46]   S1
//  [48..62]   S2
//  [64..1087] cw (1024 floats; used only by fallback path)
//  [1088 ..]  3 planes of NB*NMC per-MC partial sums (tr, te, w)
#define CW_OFF   64
#define P_OFF    1088
#define PLANE    (NB * NMC)
#define WS_SMALL 1088
#define WS_BIG   (P_OFF + 3 * PLANE)

__device__ __forceinline__ float fast_exp2(float x) {
#if __has_builtin(__builtin_amdgcn_exp2f)
    return __builtin_amdgcn_exp2f(x);
#else
    return exp2f(x);
#endif
}

// ---------------------------------------------------------------- setup ----
__global__ void setup_k(const int* __restrict__ by, const int* __restrict__ bp,
                        const float* __restrict__ trp, const float* __restrict__ tep,
                        float* __restrict__ ws)
{
    int i    = blockIdx.x * blockDim.x + threadIdx.x;
    int lane = threadIdx.x & 63;

    float c = 0.f;
    if (i < BSZ) {
        c = (by[i] == bp[i]) ? 1.f : 0.f;
        ws[CW_OFF + i] = c;
    }
    unsigned long long mc = __ballot(c != 0.f);
    if (lane == 0 && mc) atomicAdd(&ws[0], (float)__popcll(mc));

    float p_tr = (i < NTR) ? trp[i] : -1.f;
    float p_te = (i < NTE) ? tep[i] : -1.f;
    const float step = 1.0f / 15.0f;
    for (int b2 = 0; b2 < NB; b2++) {
        float lo = b2 * step;
        float hi = (b2 == NB - 1) ? 1.0f : (b2 + 1) * step;
        unsigned long long m1 = __ballot(p_tr > lo && p_tr <= hi);
        unsigned long long m2 = __ballot(p_te > lo && p_te <= hi);
        if (lane == 0) {
            if (m1) atomicAdd(&ws[1  + b2], (float)__popcll(m1));
            if (m2) atomicAdd(&ws[16 + b2], (float)__popcll(m2));
        }
    }
}

// ------------------------------------------------------------ heavy KDE ----
// R6 structure: pack 2 MC points per v2f (natural register pairs of distinct
// values -> no broadcast movs). Data point staged in LDS PRE-DUPLICATED as
// (a,a,b,b)/(c,c,w,w), so ds_read_b128 + aligned .xy/.zw extraction yields
// the {a,a} pair operands for free. Body = pk_add + 2*pk_fma + 2*exp + 2*acc.
// Padded slots: a=b=0, c=-1e30 -> exp2 -> 0.
template <bool W>
__device__ __forceinline__ void phase(const float2* __restrict__ pts,
                                      const int* __restrict__ by,
                                      const int* __restrict__ bp,
                                      int N, int slice,
                                      v4f* sAB, v4f* sCW,
                                      const v2f* qx2, const v2f* qy2, const v2f* qe2,
                                      float* accx, int tid)
{
    int L      = (N + DS - 1) / DS;
    int start  = slice * L;
    int len    = min(L, N - start);
    int rounds = (len + TILE - 1) / TILE;
    for (int r = 0; r < rounds; ++r) {
        __syncthreads();
        int o = r * TILE + tid;
        float a = 0.f, b = 0.f, c = -1e30f, wv = 0.f;
        if (o < len) {
            float2 p = pts[start + o];
            a = TWO_EXPC * p.x;
            b = TWO_EXPC * p.y;
            c = -EXPC * fmaf(p.x, p.x, p.y * p.y);
            if (W) wv = (by[start + o] == bp[start + o]) ? 1.f : 0.f;
        }
        sAB[tid] = v4f{a, a, b, b};
        sCW[tid] = v4f{c, c, wv, wv};
        __syncthreads();

        int cnt = min(TILE, len - r * TILE);
#pragma unroll 4
        for (int g = 0; g < cnt; ++g) {
            v4f AB = sAB[g];
            v4f CW = sCW[g];
            v2f a2 = AB.xy;
            v2f b2 = AB.zw;
            v2f c2 = CW.xy;
            float wsc = CW.z;
#pragma unroll
            for (int j = 0; j < MQ / 2; ++j) {
                v2f t0, t1, e;
                asm("v_pk_add_f32 %0, %1, %2"
                    : "=v"(t0) : "v"(c2), "v"(qe2[j]));
                asm("v_pk_fma_f32 %0, %1, %2, %3"
                    : "=v"(t1) : "v"(b2), "v"(qy2[j]), "v"(t0));
                asm("v_pk_fma_f32 %0, %1, %2, %3"
                    : "=v"(e) : "v"(a2), "v"(qx2[j]), "v"(t1));
                float k0 = fast_exp2(e.x);
                float k1 = fast_exp2(e.y);
                if (W) {
                    accx[2 * j]     = fmaf(wsc, k0, accx[2 * j]);
                    accx[2 * j + 1] = fmaf(wsc, k1, accx[2 * j + 1]);
                } else {
                    accx[2 * j]     += k0;
                    accx[2 * j + 1] += k1;
                }
            }
        }
    }
}

__global__ __launch_bounds__(256) void kdeA(
    const float2* __restrict__ mc2,
    const float2* __restrict__ tr2,
    const float2* __restrict__ te2,
    const float2* __restrict__ bx2,
    const int*    __restrict__ by,
    const int*    __restrict__ bp,
    float* __restrict__ P)
{
    __shared__ v4f sAB[TILE];
    __shared__ v4f sCW[TILE];

    int tid   = threadIdx.x;
    int bin   = blockIdx.y;
    int slice = blockIdx.z;
    int base  = blockIdx.x * (256 * MQ);

    int qi[MQ];
    v2f qx2[MQ / 2], qy2[MQ / 2], qe2[MQ / 2];
#pragma unroll
    for (int j = 0; j < MQ / 2; ++j) {
#pragma unroll
        for (int h = 0; h < 2; ++h) {
            int k = 2 * j + h;
            qi[k] = base + k * 256 + tid;
            int qs = qi[k] < NMC ? qi[k] : (NMC - 1);
            float2 q = mc2[bin * NMC + qs];
            float qe = -EXPC * fmaf(q.x, q.x, q.y * q.y);
            if (h == 0) { qx2[j].x = q.x; qy2[j].x = q.y; qe2[j].x = qe; }
            else        { qx2[j].y = q.x; qy2[j].y = q.y; qe2[j].y = qe; }
        }
    }

    float accx[MQ];

    // phase 1: train
#pragma unroll
    for (int k = 0; k < MQ; ++k) accx[k] = 0.f;
    phase<false>(tr2, nullptr, nullptr, NTR, slice, sAB, sCW, qx2, qy2, qe2, accx, tid);
#pragma unroll
    for (int k = 0; k < MQ; ++k)
        if (qi[k] < NMC) atomicAdd(&P[bin * NMC + qi[k]], accx[k]);

    // phase 2: test
#pragma unroll
    for (int k = 0; k < MQ; ++k) accx[k] = 0.f;
    phase<false>(te2, nullptr, nullptr, NTE, slice, sAB, sCW, qx2, qy2, qe2, accx, tid);
#pragma unroll
    for (int k = 0; k < MQ; ++k)
        if (qi[k] < NMC) atomicAdd(&P[PLANE + bin * NMC + qi[k]], accx[k]);

    // phase 3: weighted batch (weight computed inline from by==bp)
#pragma unroll
    for (int k = 0; k < MQ; ++k) accx[k] = 0.f;
    phase<true>(bx2, by, bp, BSZ, slice, sAB, sCW, qx2, qy2, qe2, accx, tid);
#pragma unroll
    for (int k = 0; k < MQ; ++k)
        if (qi[k] < NMC) atomicAdd(&P[2 * PLANE + bin * NMC + qi[k]], accx[k]);
}

// ------------------------------------------------------------- combine ----
// P holds the full kernel sums (qe inside the exponent) — no rescaling here.
__global__ void combine_k(const float2* __restrict__ mc2,
                          const float*  __restrict__ Wm,
                          const float*  __restrict__ bv,
                          const float*  __restrict__ ws,
                          const float*  __restrict__ P,
                          float* __restrict__ S1, float* __restrict__ S2)
{
    int bin  = blockIdx.y;
    int m    = blockIdx.x * 256 + threadIdx.x;
    int lane = threadIdx.x & 63;

    float c1 = 0.f, c2 = 0.f;
    if (m < NMC) {
        float2 q = mc2[bin * NMC + m];
        int idx  = bin * NMC + m;
        float t_tr = P[idx];
        float t_te = P[PLANE + idx];
        float t_w  = P[2 * PLANE + idx];

        float lmax = -1e30f;
        float l[NCLS];
#pragma unroll
        for (int c = 0; c < NCLS; ++c) {
            l[c] = fmaf(q.x, Wm[c], fmaf(q.y, Wm[NCLS + c], bv[c]));
            lmax = fmaxf(lmax, l[c]);
        }
        float sume = 0.f;
#pragma unroll
        for (int c = 0; c < NCLS; ++c) sume += expf(l[c] - lmax);
        float hat_s = 1.0f / sume;

        const float step = 1.0f / 15.0f;
        float lo = bin * step;
        float hi = (bin == NB - 1) ? 1.0f : (bin + 1) * step;
        float ind = (hat_s >= lo && hat_s <= hi) ? 1.f : 0.f;

        float cnt    = ws[0];
        float kde_tr = t_tr * (1.0f / (NTR * KDE_NORM));
        float kde_te = t_te * (1.0f / (NTE * KDE_NORM));
        float kw     = t_w / (fmaxf(cnt, 1.0f) * KDE_NORM);
        float p_y    = cnt * (1.0f / BSZ);
        float p_hs   = kw * p_y / (kde_tr + 1e-8f);
        p_hs = fminf(fmaxf(p_hs, 0.f), 1.f);

        c1 = p_hs * ind * kde_te;
        c2 = p_hs * ind * kde_tr;
    }

    for (int off = 32; off > 0; off >>= 1) {
        c1 += __shfl_down(c1, off);
        c2 += __shfl_down(c2, off);
    }
    if (lane == 0) {
        atomicAdd(&S1[bin], c1);
        atomicAdd(&S2[bin], c2);
    }
}

// ------------------------------------- fallback (small ws): R2 kernel ----
template <int ROUNDS, bool WEIGHTED>
__device__ __forceinline__ float kde_phase_fb(const float2* __restrict__ pts,
                                              int Nq, float4* tile,
                                              const float* __restrict__ w,
                                              int tid, int wid,
                                              float qx, float qy, float qe)
{
    float acc = 0.f;
    for (int r = 0; r < ROUNDS; ++r) {
        __syncthreads();
        int off = r * TILE + tid;
#pragma unroll
        for (int s = 0; s < 4; ++s) {
            float4 v;
            if (off < Nq) {
                float2 p = pts[s * Nq + off];
                v.x = TWO_EXPC * p.x;
                v.y = TWO_EXPC * p.y;
                v.z = -EXPC * fmaf(p.x, p.x, p.y * p.y);
                v.w = WEIGHTED ? w[s * Nq + off] : 0.f;
            } else {
                v = make_float4(0.f, 0.f, -1e30f, 0.f);
            }
            tile[s * TILE + tid] = v;
        }
        __syncthreads();
        const float4* t4 = &tile[wid * TILE];
#pragma unroll 8
        for (int j = 0; j < TILE; ++j) {
            float4 v = t4[j];
            float e = fmaf(qx, v.x, fmaf(qy, v.y, v.z)) + qe;
            float k = fast_exp2(e);
            acc = WEIGHTED ? fmaf(v.w, k, acc) : (acc + k);
        }
    }
    return acc;
}

__global__ __launch_bounds__(256) void ec_kde_fb(
    const float2* __restrict__ mc2, const float2* __restrict__ train2,
    const float2* __restrict__ test2, const float2* __restrict__ batch2,
    const float* __restrict__ Wm, const float* __restrict__ bv,
    const float* __restrict__ ws, float* __restrict__ S1, float* __restrict__ S2)
{
    __shared__ float4 tile[4 * TILE];
    __shared__ float  red[3][256];

    int tid  = threadIdx.x;
    int wid  = tid >> 6;
    int lane = tid & 63;
    int bin  = blockIdx.y;
    int m    = blockIdx.x * 64 + lane;
    int mm   = (m < NMC) ? m : (NMC - 1);

    float2 q = mc2[bin * NMC + mm];
    float qx = q.x, qy = q.y;
    float qe = -EXPC * fmaf(qx, qx, qy * qy);

    float s_tr = kde_phase_fb<20, false>(train2, NTR / 4, tile, nullptr, tid, wid, qx, qy, qe);
    float s_te = kde_phase_fb<10, false>(test2,  NTE / 4, tile, nullptr, tid, wid, qx, qy, qe);
    float s_w  = kde_phase_fb<1,  true >(batch2, BSZ / 4, tile, ws + CW_OFF, tid, wid, qx, qy, qe);

    red[0][tid] = s_tr; red[1][tid] = s_te; red[2][tid] = s_w;
    __syncthreads();

    if (tid < 64) {
        float t_tr = ((red[0][tid] + red[0][tid + 64]) + (red[0][tid + 128] + red[0][tid + 192]));
        float t_te = ((red[1][tid] + red[1][tid + 64]) + (red[1][tid + 128] + red[1][tid + 192]));
        float t_w  = ((red[2][tid] + red[2][tid + 64]) + (red[2][tid + 128] + red[2][tid + 192]));

        float lmax = -1e30f;
        float l[NCLS];
#pragma unroll
        for (int c = 0; c < NCLS; ++c) {
            l[c] = fmaf(qx, Wm[c], fmaf(qy, Wm[NCLS + c], bv[c]));
            lmax = fmaxf(lmax, l[c]);
        }
        float sume = 0.f;
#pragma unroll
        for (int c = 0; c < NCLS; ++c) sume += expf(l[c] - lmax);
        float hat_s = 1.0f / sume;

        const float step = 1.0f / 15.0f;
        float lo = bin * step;
        float hi = (bin == NB - 1) ? 1.0f : (bin + 1) * step;
        float ind = (hat_s >= lo && hat_s <= hi) ? 1.f : 0.f;

        float cnt    = ws[0];
        float kde_tr = t_tr * (1.0f / (NTR * KDE_NORM));
        float kde_te = t_te * (1.0f / (NTE * KDE_NORM));
        float kw     = t_w / (fmaxf(cnt, 1.0f) * KDE_NORM);
        float p_y    = cnt * (1.0f / BSZ);
        float p_hs   = kw * p_y / (kde_tr + 1e-8f);
        p_hs = fminf(fmaxf(p_hs, 0.f), 1.f);

        bool valid = (m < NMC);
        float c1 = valid ? p_hs * ind * kde_te : 0.f;
        float c2 = valid ? p_hs * ind * kde_tr : 0.f;

        for (int off = 32; off > 0; off >>= 1) {
            c1 += __shfl_down(c1, off);
            c2 += __shfl_down(c2, off);
        }
        if (lane == 0) {
            atomicAdd(&S1[bin], c1);
            atomicAdd(&S2[bin], c2);
        }
    }
}

// ---------------------------------------------------------------- final ----
__global__ void final_k(const float* __restrict__ ws, float* __restrict__ out)
{
    if (threadIdx.x == 0 && blockIdx.x == 0) {
        float ec = 0.f;
        for (int b = 0; b < NB; ++b) {
            float tr_rate = ws[1  + b] * (1.0f / NTR);
            float te_rate = ws[16 + b] * (1.0f / NTE);
            float s1 = ws[32 + b];
            float s2 = ws[48 + b];
            float a_te = (te_rate > 0.f) ? (1.0f / te_rate) : 0.f;
            float a_tr = (tr_rate > 0.f) ? (1.0f / tr_rate) : 0.f;
            float integral = (a_te * s1 - a_tr * s2) * (1.0f / NMC) * 100.0f;
            if (te_rate > 0.f) ec += te_rate * fabsf(integral);
        }
        out[0] = ec;
    }
}

// --------------------------------------------------------------- launch ----
extern "C" void kernel_launch(void* const* d_in, const int* in_sizes, int n_in,
                              void* d_out, int out_size, void* d_ws, size_t ws_size,
                              hipStream_t stream)
{
    const float* batch_x = (const float*)d_in[0];
    const int*   by      = (const int*)  d_in[1];
    const int*   bp      = (const int*)  d_in[2];
    const float* trp     = (const float*)d_in[3];
    const float* tep     = (const float*)d_in[4];
    const float* train_x = (const float*)d_in[5];
    const float* test_x  = (const float*)d_in[6];
    const float* Wm      = (const float*)d_in[7];
    const float* bv      = (const float*)d_in[8];
    const float* mc      = (const float*)d_in[9];

    float* ws  = (float*)d_ws;
    float* out = (float*)d_out;

    bool big = ws_size >= (size_t)WS_BIG * sizeof(float);
    size_t zbytes = (big ? WS_BIG : WS_SMALL) * sizeof(float);
    hipMemsetAsync(d_ws, 0, zbytes, stream);

    int nthr = 256;
    int nblk = (NTR + nthr - 1) / nthr;
    setup_k<<<nblk, nthr, 0, stream>>>(by, bp, trp, tep, ws);

    if (big) {
        dim3 gA((NMC + 256 * MQ - 1) / (256 * MQ), NB, DS);
        kdeA<<<gA, 256, 0, stream>>>(
            (const float2*)mc, (const float2*)train_x, (const float2*)test_x,
            (const float2*)batch_x, by, bp, ws + P_OFF);

        dim3 gB((NMC + 255) / 256, NB);
        combine_k<<<gB, 256, 0, stream>>>(
            (const float2*)mc, Wm, bv, ws, ws + P_OFF, ws + 32, ws + 48);
    } else {
        dim3 grid((NMC + 63) / 64, NB);
        ec_kde_fb<<<grid, 256, 0, stream>>>(
            (const float2*)mc,
            (const float2*)train_x, (const float2*)test_x, (const float2*)batch_x,
            Wm, bv, ws, ws + 32, ws + 48);
    }

    final_k<<<1, 64, 0, stream>>>(ws, out);
}